// Round 12
// baseline (6809.140 us; speedup 1.0000x reference)
//
#include <hip/hip_runtime.h>

// MyLSTM_GCN: B=4096, T=128, H=156, L=2, O=12
// R14: identical resubmit of R13 (GPUAcquisitionTimeout - never ran).
// R13: controlled ablation on the R5 winner (2434 us, best so far).
//  ONLY change: LDS A-reads (gates/GCN/proj) split b128 -> 2x volatile b64.
//  Row-major [32][168] A-tiles at 336B stride give 8-lanes/bank b128 reads
//  (lcol*84dw = period-8 mod 32); b64 at 42dw stride = 16 distinct banks,
//  ~2-way = free (m136). Global side BYTE-IDENTICAL to R5 -> direct A/B on
//  the L2-flip theory (H1: gate-loop speed triggers the 9x FETCH blowup seen
//  in R9/R10/R12).
//  Everything else verbatim R5: [32][168] tiles, per-mat A-re-reads, dbuf DMA
//  m<7?vmcnt(5):vmcnt(0) ledger, full __syncthreads, layer-split, rolling proj.

#define HH 156
#define HP 160
#define TT 128
#define OO 12
#define BB 32             // batches per WG
#define LDSS 168          // LDS row stride (f16) for A-side tiles
#define MATSZ 25600       // 160x160 f16 per matrix, frag-major

typedef _Float16 f16x8 __attribute__((ext_vector_type(8)));
typedef _Float16 f16x4 __attribute__((ext_vector_type(4)));
typedef float    f32x4 __attribute__((ext_vector_type(4)));

__device__ __forceinline__ float sigm(float v) { return 1.0f / (1.0f + __expf(-v)); }
__device__ __forceinline__ float tanh_(float v) { return 2.0f / (1.0f + __expf(-2.0f * v)) - 1.0f; }

// A-side LDS load as two b64s (volatile blocks b128 re-combining):
// 8-lanes/bank -> ~2-way on the 336B-stride row-major tiles.
__device__ __forceinline__ f16x8 lda8(const _Float16* p) {
    f16x4 lo = *(const volatile f16x4*)p;
    f16x4 hi = *(const volatile f16x4*)(p + 4);
    f16x8 r;
    r[0] = lo[0]; r[1] = lo[1]; r[2] = lo[2]; r[3] = lo[3];
    r[4] = hi[0]; r[5] = hi[1]; r[6] = hi[2]; r[7] = hi[3];
    return r;
}

// ---------------------------------------------------------------------------
// Phase 0 (unchanged, verified): 17 matrices frag-major f16 + combined biases.
// mat id: 0 = adj; 1 + j*8 + (g*2+s), g: i,f,o,c; s=0:Wx,1:Wh.
// ---------------------------------------------------------------------------
__global__ __launch_bounds__(256) void prep_kernel(
    const float* __restrict__ adj,
    const float* __restrict__ Wix, const float* __restrict__ Wih,
    const float* __restrict__ Wfx, const float* __restrict__ Wfh,
    const float* __restrict__ Wcx, const float* __restrict__ Wch,
    const float* __restrict__ Wox, const float* __restrict__ Woh,
    const float* __restrict__ bix, const float* __restrict__ bih,
    const float* __restrict__ bfx, const float* __restrict__ bfh,
    const float* __restrict__ bcx, const float* __restrict__ bch,
    const float* __restrict__ box_, const float* __restrict__ boh,
    _Float16* __restrict__ wmats, float* __restrict__ bias_comb)
{
    int idx = blockIdx.x * 256 + threadIdx.x;
    if (idx < 17 * MATSZ) {
        int mat = idx / MATSZ;
        int r   = idx % MATSZ;
        int e    = r & 7;
        int lane = (r >> 3) & 63;
        int c    = r >> 9;            // 0..49
        int lcol = lane & 15, quad = lane >> 4;
        int kk = c % 5, w = c / 5;
        int nrow = w * 16 + lcol;
        int k    = kk * 32 + quad * 8 + e;
        float v = 0.f;
        if (nrow < HH && k < HH) {
            if (mat == 0) {
                v = adj[nrow * HH + k];
            } else {
                int m2 = mat - 1;
                int s  = m2 & 1;
                int jg = m2 >> 1;
                int j  = jg >> 2;
                int g  = jg & 3;
                const float* W;
                if (s == 0) W = (g == 0) ? Wix : (g == 1) ? Wfx : (g == 2) ? Wox : Wcx;
                else        W = (g == 0) ? Wih : (g == 1) ? Wfh : (g == 2) ? Woh : Wch;
                v = W[j * (HH * HH) + nrow * HH + k];
            }
        }
        wmats[idx] = (_Float16)v;
    } else if (idx < 17 * MATSZ + 2 * 4 * HP) {
        int r = idx - 17 * MATSZ;
        int j = r / (4 * HP);
        int g = (r % (4 * HP)) / HP;
        int nn = r % HP;
        float v = 0.f;
        if (nn < HH) {
            const float* Bx = (g == 0) ? bix : (g == 1) ? bfx : (g == 2) ? box_ : bcx;
            const float* Bh = (g == 0) ? bih : (g == 1) ? bfh : (g == 2) ? boh : bch;
            v = Bx[j * HH + nn] + Bh[j * HH + nn];
        }
        bias_comb[r] = v;
    }
}

// async 16B/lane DMA: lane L reads g+L*16B, writes wave-uniform ldsbase + L*16B
__device__ __forceinline__ void dma16(const _Float16* g, _Float16* l) {
    __builtin_amdgcn_global_load_lds(
        (const __attribute__((address_space(1))) void*)(g),
        (__attribute__((address_space(3))) void*)(l), 16, 0, 0);
}

// stage one frag-major matrix: wave w copies its own chunks w*5..w*5+4 (1KB each)
__device__ __forceinline__ void stage_mat(_Float16* buf, const _Float16* gmat,
                                          int wave, int lane) {
    #pragma unroll
    for (int i = 0; i < 5; ++i) {
        const int c = wave * 5 + i;
        dma16(gmat + (size_t)c * 512 + lane * 8, buf + (size_t)c * 512);
    }
}

// ---------------------------------------------------------------------------
// Main recurrent kernel: 256 WGs x 640 threads (10 waves, 1 WG/CU).
// bid&1 = layer (even/odd XCD co-location), bid>>1 = batch group (M=32).
// Wave w owns feature columns n = w*16 + (lane&15).
// ---------------------------------------------------------------------------
__global__ __launch_bounds__(640, 3) void lstm_main(
    const float* __restrict__ x,
    const _Float16* __restrict__ wmats,
    const float* __restrict__ bias_comb,
    const float* __restrict__ w_out,
    const float* __restrict__ b_out,
    const float* __restrict__ gcn_w1,
    const float* __restrict__ gcn_w2,
    float* __restrict__ out)
{
    __shared__ __align__(16) _Float16 st_c[BB][LDSS];
    __shared__ __align__(16) _Float16 st_h[BB][LDSS];
    __shared__ __align__(16) _Float16 tmp[BB][LDSS];
    __shared__ __align__(16) _Float16 xb[BB][LDSS];
    __shared__ __align__(16) _Float16 wout_s[OO][TT + 8];
    extern __shared__ __align__(16) _Float16 wbuf[];   // 2 x 25600 f16 (100 KB)

    const int tid   = threadIdx.x;
    const int wave  = tid >> 6;
    const int lane  = tid & 63;
    const int lcol  = lane & 15;
    const int quad  = lane >> 4;
    const int qoff  = quad << 3;
    const int layer = blockIdx.x & 1;
    const int b0    = (blockIdx.x >> 1) << 5;
    const int n     = (wave << 4) + lcol;

    for (int e = tid; e < BB * LDSS; e += 640) {
        (&st_c[0][0])[e] = (_Float16)0.f;
        (&st_h[0][0])[e] = (_Float16)0.f;
        (&xb[0][0])[e]   = (_Float16)0.f;
    }
    for (int e = tid; e < OO * TT; e += 640) wout_s[e / TT][e % TT] = (_Float16)w_out[e];

    float bias_r[4];
    #pragma unroll
    for (int g = 0; g < 4; ++g)
        bias_r[g] = bias_comb[(layer * 4 + g) * HP + n];
    const float gw1 = gcn_w1[layer];
    const float gw2 = gcn_w2[layer];
    const float bout_r = (lcol < OO) ? b_out[lcol] : 0.f;

    // adj B-frags: register-resident all 128 steps (frag-major id 0)
    f16x8 badj[5];
    #pragma unroll
    for (int kk = 0; kk < 5; ++kk)
        badj[kk] = *(const f16x8*)&wmats[((size_t)(wave * 5 + kk) * 64 + lane) * 8];

    const _Float16* gw = wmats + (size_t)(1 + layer * 8) * MATSZ;  // this layer's 8 mats
    __syncthreads();

    // rolling projection accumulator (layer-1 WGs, waves 0-5: slot=wave>>1, mt=wave&1)
    f32x4 pacc = {0.f, 0.f, 0.f, 0.f};
    int cur_i = wave >> 1;            // planes cycle slot = i mod 3
    const int pmt = wave & 1;

    auto proj_step = [&](int tp) {
        if (cur_i > HH - 1) return;
        const int s = cur_i * TT - tp * HH;   // t' = f - s
        if (s > HH - 1) return;               // plane not yet in window
        const int lc = (lcol < OO) ? lcol : 0;
        #pragma unroll
        for (int kk = 0; kk < 5; ++kk) {
            f16x8 b;
            #pragma unroll
            for (int e = 0; e < 8; ++e) {
                int f  = kk * 32 + qoff + e;
                int tq = f - s;
                bool ok = (lcol < OO) && (tq >= 0) && (tq < TT) && (f < HH);
                int tqc = tq < 0 ? 0 : (tq > TT - 1 ? TT - 1 : tq);
                b[e] = ok ? wout_s[lc][tqc] : (_Float16)0.f;
            }
            f16x8 a = lda8(&st_h[pmt * 16 + lcol][kk * 32 + qoff]);
            pacc = __builtin_amdgcn_mfma_f32_16x16x32_f16(a, b, pacc, 0, 0, 0);
        }
        if (s <= 28) {        // t_last(cur_i) == tp: plane complete -> pure store
            if (lcol < OO) {
                #pragma unroll
                for (int r = 0; r < 4; ++r)
                    out[(size_t)(b0 + pmt * 16 + (quad << 2) + r) * (HH * OO)
                        + cur_i * OO + lcol] = pacc[r] + bout_r;
            }
            pacc = (f32x4){0.f, 0.f, 0.f, 0.f};
            cur_i += 3;
        }
    };

    for (int t = 0; t < TT; ++t) {
        // ---- phase A ----------------------------------------------------
        // waves 6-9: issue x loads FIRST (so their wait doesn't drain DMAs)
        float4 vx[5];
        if (wave >= 6) {
            const int e0 = tid - 384;
            #pragma unroll
            for (int it = 0; it < 5; ++it) {
                int e = e0 + it * 256;          // 0..1279
                int m = e / 40, q = e % 40, f = q << 2;
                float4 v = make_float4(0.f, 0.f, 0.f, 0.f);
                if (f + 4 <= HH) v = *(const float4*)&x[((size_t)(b0 + m) * TT + t) * HH + f];
                vx[it] = v;
            }
        }
        // DMA mats 0,1 of this step into both buffers (per-wave own chunks)
        stage_mat(wbuf,          gw,          wave, lane);
        stage_mat(wbuf + MATSZ,  gw + MATSZ,  wave, lane);

        if (wave >= 6) {
            const int e0 = tid - 384;
            #pragma unroll
            for (int it = 0; it < 5; ++it) {
                int e = e0 + it * 256;
                int m = e / 40, q = e % 40, f = q << 2;
                f16x4 h4 = {(_Float16)vx[it].x, (_Float16)vx[it].y,
                            (_Float16)vx[it].z, (_Float16)vx[it].w};
                *(f16x4*)&xb[m][f] = h4;       // f=156 chunk writes zeros into pad
            }
        } else if (layer && t > 0) {
            proj_step(t - 1);
        }
        __syncthreads();   // B1: xb ready, proj reads done, states stable

        // ---- GCN (t>0): per state matrix, badj from regs --------------------
        if (t > 0) {
            #pragma unroll
            for (int S = 0; S < 2; ++S) {       // 0: c, 1: h
                const _Float16* Ab = S ? &st_h[0][0] : &st_c[0][0];
                // stage 1: tmp = relu(w1 * (state @ adj^T))
                #pragma unroll
                for (int mt = 0; mt < 2; ++mt) {
                    f32x4 acc = {0.f, 0.f, 0.f, 0.f};
                    #pragma unroll
                    for (int kk = 0; kk < 5; ++kk) {
                        f16x8 a = lda8(&Ab[(size_t)(mt * 16 + lcol) * LDSS + kk * 32 + qoff]);
                        acc = __builtin_amdgcn_mfma_f32_16x16x32_f16(a, badj[kk], acc, 0, 0, 0);
                    }
                    #pragma unroll
                    for (int r = 0; r < 4; ++r) {
                        float v = acc[r] * gw1;
                        tmp[mt * 16 + (quad << 2) + r][n] = (_Float16)(v > 0.f ? v : 0.f);
                    }
                }
                __syncthreads();
                // stage 2: state = sigmoid(w2 * (tmp @ adj^T))
                _Float16 (*dst)[LDSS] = S ? st_h : st_c;
                #pragma unroll
                for (int mt = 0; mt < 2; ++mt) {
                    f32x4 acc = {0.f, 0.f, 0.f, 0.f};
                    #pragma unroll
                    for (int kk = 0; kk < 5; ++kk) {
                        f16x8 a = lda8(&tmp[mt * 16 + lcol][kk * 32 + qoff]);
                        acc = __builtin_amdgcn_mfma_f32_16x16x32_f16(a, badj[kk], acc, 0, 0, 0);
                    }
                    #pragma unroll
                    for (int r = 0; r < 4; ++r)
                        dst[mt * 16 + (quad << 2) + r][n] = (_Float16)sigm(acc[r] * gw2);
                }
                __syncthreads();
            }
        }

        // ---- gates: 8 matrices, dbuf DMA stream, NO barriers ---------------
        // per-wave pipeline: counted vmcnt; wave reads only its own chunks.
        f32x4 acc[8];     // 4 gates x 2 M-tiles
        #pragma unroll
        for (int a2 = 0; a2 < 8; ++a2) acc[a2] = (f32x4){0.f, 0.f, 0.f, 0.f};
        #pragma unroll
        for (int m = 0; m < 8; ++m) {
            if (m < 7) asm volatile("s_waitcnt vmcnt(5)" ::: "memory");
            else       asm volatile("s_waitcnt vmcnt(0)" ::: "memory");
            __builtin_amdgcn_sched_barrier(0);
            const _Float16* wbc = wbuf + (size_t)(m & 1) * MATSZ;
            f16x8 bw[5];
            #pragma unroll
            for (int kk = 0; kk < 5; ++kk)
                bw[kk] = *(const f16x8*)&wbc[((size_t)(wave * 5 + kk) * 64 + lane) * 8];
            const _Float16* Ab = (m & 1) ? &st_h[0][0] : &xb[0][0];
            const int g = m >> 1;
            #pragma unroll
            for (int mt = 0; mt < 2; ++mt) {
                #pragma unroll
                for (int kk = 0; kk < 5; ++kk) {
                    f16x8 a = lda8(&Ab[(size_t)(mt * 16 + lcol) * LDSS + kk * 32 + qoff]);
                    acc[g * 2 + mt] = __builtin_amdgcn_mfma_f32_16x16x32_f16(
                        a, bw[kk], acc[g * 2 + mt], 0, 0, 0);
                }
            }
            __builtin_amdgcn_sched_barrier(0);
            if (m + 2 < 8)
                stage_mat(wbuf + (size_t)(m & 1) * MATSZ, gw + (size_t)(m + 2) * MATSZ,
                          wave, lane);
        }
        __syncthreads();   // B4: all st_h/xb A-reads done before update writes

        // ---- elementwise LSTM update ----
        #pragma unroll
        for (int mt = 0; mt < 2; ++mt) {
            #pragma unroll
            for (int r = 0; r < 4; ++r) {
                int m = mt * 16 + (quad << 2) + r;
                float i_ = sigm(acc[0 * 2 + mt][r] + bias_r[0]);
                float f_ = sigm(acc[1 * 2 + mt][r] + bias_r[1]);
                float o_ = sigm(acc[2 * 2 + mt][r] + bias_r[2]);
                float g_ = tanh_(acc[3 * 2 + mt][r] + bias_r[3]);
                float c_old = (float)st_c[m][n];
                float c_new = f_ * c_old + i_ * g_;
                float h_new = o_ * tanh_(c_new);
                st_c[m][n] = (_Float16)c_new;
                st_h[m][n] = (_Float16)h_new;
            }
        }
        __syncthreads();   // B5: updates visible to next phase A / GCN
    }

    // final projection for t=127 (flushes all remaining planes) + epilogue
    if (layer && wave < 6) proj_step(TT - 1);

    float* hn = out + (size_t)4096 * HH * OO;
    float* cn = hn + (size_t)2 * 4096 * HH;
    for (int e = tid; e < BB * HH; e += 640) {
        int m = e / HH;
        int f = e % HH;
        size_t off = ((size_t)layer * 4096 + b0 + m) * HH + f;
        hn[off] = (float)st_h[m][f];
        cn[off] = (float)st_c[m][f];
    }
}

// ---------------------------------------------------------------------------
extern "C" void kernel_launch(void* const* d_in, const int* in_sizes, int n_in,
                              void* d_out, int out_size, void* d_ws, size_t ws_size,
                              hipStream_t stream) {
    const float* x    = (const float*)d_in[0];
    const float* adj  = (const float*)d_in[1];
    const float* Wix  = (const float*)d_in[2];  const float* bix = (const float*)d_in[3];
    const float* Wih  = (const float*)d_in[4];  const float* bih = (const float*)d_in[5];
    const float* Wfx  = (const float*)d_in[6];  const float* bfx = (const float*)d_in[7];
    const float* Wfh  = (const float*)d_in[8];  const float* bfh = (const float*)d_in[9];
    const float* Wcx  = (const float*)d_in[10]; const float* bcx = (const float*)d_in[11];
    const float* Wch  = (const float*)d_in[12]; const float* bch = (const float*)d_in[13];
    const float* Wox  = (const float*)d_in[14]; const float* box_ = (const float*)d_in[15];
    const float* Woh  = (const float*)d_in[16]; const float* boh = (const float*)d_in[17];
    const float* gw1  = (const float*)d_in[18];
    const float* gw2  = (const float*)d_in[19];
    const float* Wout = (const float*)d_in[20];
    const float* bout = (const float*)d_in[21];

    _Float16* wmats   = (_Float16*)d_ws;
    float* bias_comb  = (float*)((char*)d_ws + (size_t)17 * MATSZ * sizeof(_Float16));
    float* out        = (float*)d_out;

    prep_kernel<<<(17 * MATSZ + 2 * 4 * HP + 255) / 256, 256, 0, stream>>>(
        adj, Wix, Wih, Wfx, Wfh, Wcx, Wch, Wox, Woh,
        bix, bih, bfx, bfh, bcx, bch, box_, boh, wmats, bias_comb);

    (void)hipFuncSetAttribute((const void*)lstm_main,
                              hipFuncAttributeMaxDynamicSharedMemorySize,
                              2 * MATSZ * sizeof(_Float16));

    lstm_main<<<256, 640, 2 * MATSZ * sizeof(_Float16), stream>>>(
        x, wmats, bias_comb, Wout, bout, gw1, gw2, out);
}

// Round 13
// 2425.151 us; speedup vs baseline: 2.8077x; 2.8077x over previous
//
#include <hip/hip_runtime.h>

// MyLSTM_GCN: B=4096, T=128, H=156, L=2, O=12
// R15: BYTE-IDENTICAL code resubmit of R5/R7 (session best, 2434 us) as a
// reproduction experiment. Six rounds of evidence say time == L2-miss bytes /
// 1.3 TB/s; R5 uniquely hit compulsory-only FETCH (4.9e5 KB). R14 falsified
// the last code-side theory (slower LDS loop, byte-identical global stream,
// WORST fetch 8e6; conflict count unchanged 1.663e8). Question answered by
// this run: is R5's L2-resident state source-determined (expect ~2.4 ms,
// FETCH 5e5) or environmental (expect ~3.2 ms, FETCH ~4e6)?
//  Structure (verified): frag-major weights in ws; global_load_lds dbuf
//  2x50KB; per-wave-own-chunk DMA+read, ledger m<7?vmcnt(5):vmcnt(0);
//  layer-split 256 WGs; rolling register proj; full __syncthreads skeleton.

#define HH 156
#define HP 160
#define TT 128
#define OO 12
#define BB 32             // batches per WG
#define LDSS 168          // LDS row stride (f16) for A-side tiles
#define MATSZ 25600       // 160x160 f16 per matrix, frag-major

typedef _Float16 f16x8 __attribute__((ext_vector_type(8)));
typedef _Float16 f16x4 __attribute__((ext_vector_type(4)));
typedef float    f32x4 __attribute__((ext_vector_type(4)));

__device__ __forceinline__ float sigm(float v) { return 1.0f / (1.0f + __expf(-v)); }
__device__ __forceinline__ float tanh_(float v) { return 2.0f / (1.0f + __expf(-2.0f * v)) - 1.0f; }

// ---------------------------------------------------------------------------
// Phase 0: transcode 17 matrices (adj + 2 layers x 8 gate mats) to FRAG-MAJOR
// f16: fidx = ((c*64 + lane)*8 + e), c = w*5+kk, lane = quad*16+lcol,
// value = W[n=16w+lcol][k=32kk+8quad+e] (zero-padded past 156).
// mat id: 0 = adj; 1 + j*8 + (g*2+s), gate order g: i,f,o,c; s=0:Wx, 1:Wh.
// bias_comb[(j*4+g)*160 + n] = bx + bh (f32).
// ---------------------------------------------------------------------------
__global__ __launch_bounds__(256) void prep_kernel(
    const float* __restrict__ adj,
    const float* __restrict__ Wix, const float* __restrict__ Wih,
    const float* __restrict__ Wfx, const float* __restrict__ Wfh,
    const float* __restrict__ Wcx, const float* __restrict__ Wch,
    const float* __restrict__ Wox, const float* __restrict__ Woh,
    const float* __restrict__ bix, const float* __restrict__ bih,
    const float* __restrict__ bfx, const float* __restrict__ bfh,
    const float* __restrict__ bcx, const float* __restrict__ bch,
    const float* __restrict__ box_, const float* __restrict__ boh,
    _Float16* __restrict__ wmats, float* __restrict__ bias_comb)
{
    int idx = blockIdx.x * 256 + threadIdx.x;
    if (idx < 17 * MATSZ) {
        int mat = idx / MATSZ;
        int r   = idx % MATSZ;
        int e    = r & 7;
        int lane = (r >> 3) & 63;
        int c    = r >> 9;            // 0..49
        int lcol = lane & 15, quad = lane >> 4;
        int kk = c % 5, w = c / 5;
        int nrow = w * 16 + lcol;
        int k    = kk * 32 + quad * 8 + e;
        float v = 0.f;
        if (nrow < HH && k < HH) {
            if (mat == 0) {
                v = adj[nrow * HH + k];
            } else {
                int m2 = mat - 1;
                int s  = m2 & 1;
                int jg = m2 >> 1;          // j*4 + g
                int j  = jg >> 2;
                int g  = jg & 3;
                const float* W;
                if (s == 0) W = (g == 0) ? Wix : (g == 1) ? Wfx : (g == 2) ? Wox : Wcx;
                else        W = (g == 0) ? Wih : (g == 1) ? Wfh : (g == 2) ? Woh : Wch;
                v = W[j * (HH * HH) + nrow * HH + k];
            }
        }
        wmats[idx] = (_Float16)v;
    } else if (idx < 17 * MATSZ + 2 * 4 * HP) {
        int r = idx - 17 * MATSZ;
        int j = r / (4 * HP);
        int g = (r % (4 * HP)) / HP;
        int nn = r % HP;
        float v = 0.f;
        if (nn < HH) {
            const float* Bx = (g == 0) ? bix : (g == 1) ? bfx : (g == 2) ? box_ : bcx;
            const float* Bh = (g == 0) ? bih : (g == 1) ? bfh : (g == 2) ? boh : bch;
            v = Bx[j * HH + nn] + Bh[j * HH + nn];
        }
        bias_comb[r] = v;
    }
}

// async 16B/lane DMA: lane L reads g+L*16B, writes ldsbase + L*16B
__device__ __forceinline__ void dma16(const _Float16* g, _Float16* l) {
    __builtin_amdgcn_global_load_lds(
        (const __attribute__((address_space(1))) void*)(g),
        (__attribute__((address_space(3))) void*)(l), 16, 0, 0);
}

// stage one frag-major matrix: wave w copies its own chunks w*5..w*5+4 (1KB each)
__device__ __forceinline__ void stage_mat(_Float16* buf, const _Float16* gmat,
                                          int wave, int lane) {
    #pragma unroll
    for (int i = 0; i < 5; ++i) {
        const int c = wave * 5 + i;
        dma16(gmat + (size_t)c * 512 + lane * 8, buf + (size_t)c * 512);
    }
}

// ---------------------------------------------------------------------------
// Main recurrent kernel: 256 WGs x 640 threads (10 waves, 1 WG/CU).
// bid&1 = layer (even/odd XCD co-location), bid>>1 = batch group (M=32).
// Wave w owns feature columns n = w*16 + (lane&15).
// ---------------------------------------------------------------------------
__global__ __launch_bounds__(640, 3) void lstm_main(
    const float* __restrict__ x,
    const _Float16* __restrict__ wmats,
    const float* __restrict__ bias_comb,
    const float* __restrict__ w_out,
    const float* __restrict__ b_out,
    const float* __restrict__ gcn_w1,
    const float* __restrict__ gcn_w2,
    float* __restrict__ out)
{
    __shared__ __align__(16) _Float16 st_c[BB][LDSS];
    __shared__ __align__(16) _Float16 st_h[BB][LDSS];
    __shared__ __align__(16) _Float16 tmp[BB][LDSS];
    __shared__ __align__(16) _Float16 xb[BB][LDSS];
    __shared__ __align__(16) _Float16 wout_s[OO][TT + 8];
    extern __shared__ __align__(16) _Float16 wbuf[];   // 2 x 25600 f16 (100 KB)

    const int tid   = threadIdx.x;
    const int wave  = tid >> 6;
    const int lane  = tid & 63;
    const int lcol  = lane & 15;
    const int quad  = lane >> 4;
    const int qoff  = quad << 3;
    const int layer = blockIdx.x & 1;
    const int b0    = (blockIdx.x >> 1) << 5;
    const int n     = (wave << 4) + lcol;

    for (int e = tid; e < BB * LDSS; e += 640) {
        (&st_c[0][0])[e] = (_Float16)0.f;
        (&st_h[0][0])[e] = (_Float16)0.f;
        (&xb[0][0])[e]   = (_Float16)0.f;
    }
    for (int e = tid; e < OO * TT; e += 640) wout_s[e / TT][e % TT] = (_Float16)w_out[e];

    float bias_r[4];
    #pragma unroll
    for (int g = 0; g < 4; ++g)
        bias_r[g] = bias_comb[(layer * 4 + g) * HP + n];
    const float gw1 = gcn_w1[layer];
    const float gw2 = gcn_w2[layer];
    const float bout_r = (lcol < OO) ? b_out[lcol] : 0.f;

    // adj B-frags: register-resident all 128 steps (frag-major id 0)
    f16x8 badj[5];
    #pragma unroll
    for (int kk = 0; kk < 5; ++kk)
        badj[kk] = *(const f16x8*)&wmats[((size_t)(wave * 5 + kk) * 64 + lane) * 8];

    const _Float16* gw = wmats + (size_t)(1 + layer * 8) * MATSZ;  // this layer's 8 mats
    __syncthreads();

    // rolling projection accumulator (layer-1 WGs, waves 0-5: slot=wave>>1, mt=wave&1)
    f32x4 pacc = {0.f, 0.f, 0.f, 0.f};
    int cur_i = wave >> 1;            // planes cycle slot = i mod 3
    const int pmt = wave & 1;

    auto proj_step = [&](int tp) {
        if (cur_i > HH - 1) return;
        const int s = cur_i * TT - tp * HH;   // t' = f - s
        if (s > HH - 1) return;               // plane not yet in window
        const int lc = (lcol < OO) ? lcol : 0;
        #pragma unroll
        for (int kk = 0; kk < 5; ++kk) {
            f16x8 b;
            #pragma unroll
            for (int e = 0; e < 8; ++e) {
                int f  = kk * 32 + qoff + e;
                int tq = f - s;
                bool ok = (lcol < OO) && (tq >= 0) && (tq < TT) && (f < HH);
                int tqc = tq < 0 ? 0 : (tq > TT - 1 ? TT - 1 : tq);
                b[e] = ok ? wout_s[lc][tqc] : (_Float16)0.f;
            }
            f16x8 a = *(const f16x8*)&st_h[pmt * 16 + lcol][kk * 32 + qoff];
            pacc = __builtin_amdgcn_mfma_f32_16x16x32_f16(a, b, pacc, 0, 0, 0);
        }
        if (s <= 28) {        // t_last(cur_i) == tp: plane complete -> pure store
            if (lcol < OO) {
                #pragma unroll
                for (int r = 0; r < 4; ++r)
                    out[(size_t)(b0 + pmt * 16 + (quad << 2) + r) * (HH * OO)
                        + cur_i * OO + lcol] = pacc[r] + bout_r;
            }
            pacc = (f32x4){0.f, 0.f, 0.f, 0.f};
            cur_i += 3;
        }
    };

    for (int t = 0; t < TT; ++t) {
        // ---- phase A ----------------------------------------------------
        // waves 6-9: issue x loads FIRST (so their wait doesn't drain DMAs)
        float4 vx[5];
        if (wave >= 6) {
            const int e0 = tid - 384;
            #pragma unroll
            for (int it = 0; it < 5; ++it) {
                int e = e0 + it * 256;          // 0..1279
                int m = e / 40, q = e % 40, f = q << 2;
                float4 v = make_float4(0.f, 0.f, 0.f, 0.f);
                if (f + 4 <= HH) v = *(const float4*)&x[((size_t)(b0 + m) * TT + t) * HH + f];
                vx[it] = v;
            }
        }
        // DMA mats 0,1 of this step into both buffers (per-wave own chunks)
        stage_mat(wbuf,          gw,          wave, lane);
        stage_mat(wbuf + MATSZ,  gw + MATSZ,  wave, lane);

        if (wave >= 6) {
            const int e0 = tid - 384;
            #pragma unroll
            for (int it = 0; it < 5; ++it) {
                int e = e0 + it * 256;
                int m = e / 40, q = e % 40, f = q << 2;
                f16x4 h4 = {(_Float16)vx[it].x, (_Float16)vx[it].y,
                            (_Float16)vx[it].z, (_Float16)vx[it].w};
                *(f16x4*)&xb[m][f] = h4;       // f=156 chunk writes zeros into pad
            }
        } else if (layer && t > 0) {
            proj_step(t - 1);
        }
        __syncthreads();   // B1: xb ready, proj reads done, states stable

        // ---- GCN (t>0): per state matrix, badj from regs --------------------
        if (t > 0) {
            #pragma unroll
            for (int S = 0; S < 2; ++S) {       // 0: c, 1: h
                const _Float16* Ab = S ? &st_h[0][0] : &st_c[0][0];
                // stage 1: tmp = relu(w1 * (state @ adj^T))
                #pragma unroll
                for (int mt = 0; mt < 2; ++mt) {
                    f32x4 acc = {0.f, 0.f, 0.f, 0.f};
                    #pragma unroll
                    for (int kk = 0; kk < 5; ++kk) {
                        f16x8 a = *(const f16x8*)&Ab[(size_t)(mt * 16 + lcol) * LDSS + kk * 32 + qoff];
                        acc = __builtin_amdgcn_mfma_f32_16x16x32_f16(a, badj[kk], acc, 0, 0, 0);
                    }
                    #pragma unroll
                    for (int r = 0; r < 4; ++r) {
                        float v = acc[r] * gw1;
                        tmp[mt * 16 + (quad << 2) + r][n] = (_Float16)(v > 0.f ? v : 0.f);
                    }
                }
                __syncthreads();
                // stage 2: state = sigmoid(w2 * (tmp @ adj^T))
                _Float16 (*dst)[LDSS] = S ? st_h : st_c;
                #pragma unroll
                for (int mt = 0; mt < 2; ++mt) {
                    f32x4 acc = {0.f, 0.f, 0.f, 0.f};
                    #pragma unroll
                    for (int kk = 0; kk < 5; ++kk) {
                        f16x8 a = *(const f16x8*)&tmp[mt * 16 + lcol][kk * 32 + qoff];
                        acc = __builtin_amdgcn_mfma_f32_16x16x32_f16(a, badj[kk], acc, 0, 0, 0);
                    }
                    #pragma unroll
                    for (int r = 0; r < 4; ++r)
                        dst[mt * 16 + (quad << 2) + r][n] = (_Float16)sigm(acc[r] * gw2);
                }
                __syncthreads();
            }
        }

        // ---- gates: 8 matrices, dbuf DMA stream, NO barriers ---------------
        // per-wave pipeline: counted vmcnt; wave reads only its own chunks.
        f32x4 acc[8];     // 4 gates x 2 M-tiles
        #pragma unroll
        for (int a2 = 0; a2 < 8; ++a2) acc[a2] = (f32x4){0.f, 0.f, 0.f, 0.f};
        #pragma unroll
        for (int m = 0; m < 8; ++m) {
            if (m < 7) asm volatile("s_waitcnt vmcnt(5)" ::: "memory");
            else       asm volatile("s_waitcnt vmcnt(0)" ::: "memory");
            __builtin_amdgcn_sched_barrier(0);
            const _Float16* wbc = wbuf + (size_t)(m & 1) * MATSZ;
            f16x8 bw[5];
            #pragma unroll
            for (int kk = 0; kk < 5; ++kk)
                bw[kk] = *(const f16x8*)&wbc[((size_t)(wave * 5 + kk) * 64 + lane) * 8];
            const _Float16* Ab = (m & 1) ? &st_h[0][0] : &xb[0][0];
            const int g = m >> 1;
            #pragma unroll
            for (int mt = 0; mt < 2; ++mt) {
                #pragma unroll
                for (int kk = 0; kk < 5; ++kk) {
                    f16x8 a = *(const f16x8*)&Ab[(size_t)(mt * 16 + lcol) * LDSS + kk * 32 + qoff];
                    acc[g * 2 + mt] = __builtin_amdgcn_mfma_f32_16x16x32_f16(
                        a, bw[kk], acc[g * 2 + mt], 0, 0, 0);
                }
            }
            __builtin_amdgcn_sched_barrier(0);
            if (m + 2 < 8)
                stage_mat(wbuf + (size_t)(m & 1) * MATSZ, gw + (size_t)(m + 2) * MATSZ,
                          wave, lane);
        }
        __syncthreads();   // B4: all st_h/xb A-reads done before update writes

        // ---- elementwise LSTM update ----
        #pragma unroll
        for (int mt = 0; mt < 2; ++mt) {
            #pragma unroll
            for (int r = 0; r < 4; ++r) {
                int m = mt * 16 + (quad << 2) + r;
                float i_ = sigm(acc[0 * 2 + mt][r] + bias_r[0]);
                float f_ = sigm(acc[1 * 2 + mt][r] + bias_r[1]);
                float o_ = sigm(acc[2 * 2 + mt][r] + bias_r[2]);
                float g_ = tanh_(acc[3 * 2 + mt][r] + bias_r[3]);
                float c_old = (float)st_c[m][n];
                float c_new = f_ * c_old + i_ * g_;
                float h_new = o_ * tanh_(c_new);
                st_c[m][n] = (_Float16)c_new;
                st_h[m][n] = (_Float16)h_new;
            }
        }
        __syncthreads();   // B5: updates visible to next phase A / GCN
    }

    // final projection for t=127 (flushes all remaining planes) + epilogue
    if (layer && wave < 6) proj_step(TT - 1);

    float* hn = out + (size_t)4096 * HH * OO;
    float* cn = hn + (size_t)2 * 4096 * HH;
    for (int e = tid; e < BB * HH; e += 640) {
        int m = e / HH;
        int f = e % HH;
        size_t off = ((size_t)layer * 4096 + b0 + m) * HH + f;
        hn[off] = (float)st_h[m][f];
        cn[off] = (float)st_c[m][f];
    }
}

// ---------------------------------------------------------------------------
extern "C" void kernel_launch(void* const* d_in, const int* in_sizes, int n_in,
                              void* d_out, int out_size, void* d_ws, size_t ws_size,
                              hipStream_t stream) {
    const float* x    = (const float*)d_in[0];
    const float* adj  = (const float*)d_in[1];
    const float* Wix  = (const float*)d_in[2];  const float* bix = (const float*)d_in[3];
    const float* Wih  = (const float*)d_in[4];  const float* bih = (const float*)d_in[5];
    const float* Wfx  = (const float*)d_in[6];  const float* bfx = (const float*)d_in[7];
    const float* Wfh  = (const float*)d_in[8];  const float* bfh = (const float*)d_in[9];
    const float* Wcx  = (const float*)d_in[10]; const float* bcx = (const float*)d_in[11];
    const float* Wch  = (const float*)d_in[12]; const float* bch = (const float*)d_in[13];
    const float* Wox  = (const float*)d_in[14]; const float* box_ = (const float*)d_in[15];
    const float* Woh  = (const float*)d_in[16]; const float* boh = (const float*)d_in[17];
    const float* gw1  = (const float*)d_in[18];
    const float* gw2  = (const float*)d_in[19];
    const float* Wout = (const float*)d_in[20];
    const float* bout = (const float*)d_in[21];

    _Float16* wmats   = (_Float16*)d_ws;
    float* bias_comb  = (float*)((char*)d_ws + (size_t)17 * MATSZ * sizeof(_Float16));
    float* out        = (float*)d_out;

    prep_kernel<<<(17 * MATSZ + 2 * 4 * HP + 255) / 256, 256, 0, stream>>>(
        adj, Wix, Wih, Wfx, Wfh, Wcx, Wch, Wox, Woh,
        bix, bih, bfx, bfh, bcx, bch, box_, boh, wmats, bias_comb);

    (void)hipFuncSetAttribute((const void*)lstm_main,
                              hipFuncAttributeMaxDynamicSharedMemorySize,
                              2 * MATSZ * sizeof(_Float16));

    lstm_main<<<256, 640, 2 * MATSZ * sizeof(_Float16), stream>>>(
        x, wmats, bias_comb, Wout, bout, gw1, gw2, out);
}